// Round 9
// baseline (338.764 us; speedup 1.0000x reference)
//
#include <hip/hip_runtime.h>
#include <hip/hip_cooperative_groups.h>

namespace cg = cooperative_groups;

#define NODES 50000
#define CH 128
#define ELLW 64

using frag_ab = __attribute__((ext_vector_type(8))) short;   // 8 bf16
using frag_cd = __attribute__((ext_vector_type(4))) float;   // 4 fp32

__device__ __forceinline__ float bf2f(ushort u) {
    union { unsigned u; float f; } v; v.u = ((unsigned)u) << 16; return v.f;
}
__device__ __forceinline__ ushort f2bf(float f) {
    union { float f; unsigned u; } v; v.f = f;
    unsigned r = v.u + 0x7fff + ((v.u >> 16) & 1);   // RNE
    return (ushort)(r >> 16);
}

// ================= roles (round-6 kernel bodies, extracted) =================

__device__ __forceinline__ void prep_role(int b, int tid,
    const float* __restrict__ Wlin, const float* __restrict__ W1l,
    const float* __restrict__ W1r, const float* __restrict__ W2l,
    const float* __restrict__ W2r,
    ushort* __restrict__ o0, ushort* __restrict__ o1, ushort* __restrict__ o2,
    ushort* __restrict__ o3, ushort* __restrict__ o4)
{
    const float* W; ushort* O; int K; int kb;
    if (b < 192) { W = Wlin; O = o0; K = 384; kb = b; }
    else {
        int j = (b - 192) >> 6; kb = (b - 192) & 63; K = 128;
        W = (j == 0) ? W1l : (j == 1) ? W1r : (j == 2) ? W2l : W2r;
        O = (j == 0) ? o1  : (j == 1) ? o2  : (j == 2) ? o3  : o4;
    }
    int k = kb * 2 + (tid >> 7);
    int n = tid & 127;
    if (k < K) O[(size_t)n * K + k] = f2bf(W[(size_t)k * 128 + n]);
}

// edge fill: global-atomic slot claim (proven floor ~55us; packed counters — spreading neutral)
__device__ __forceinline__ void fill_role(int fb, int tid,
    const int* __restrict__ ei, int E, int* __restrict__ degs, ushort* __restrict__ ell)
{
    int e0 = (fb * 256 + tid) * 4;
    if (e0 >= E) return;
    int s[4], dd[4], cnt;
    if (((E & 3) == 0) && (e0 + 3 < E)) {
        int4 sv = *(const int4*)(ei + e0);
        int4 dv = *(const int4*)(ei + E + e0);
        s[0] = sv.x; s[1] = sv.y; s[2] = sv.z; s[3] = sv.w;
        dd[0] = dv.x; dd[1] = dv.y; dd[2] = dv.z; dd[3] = dv.w;
        cnt = 4;
    } else {
        cnt = E - e0; if (cnt > 4) cnt = 4;
#pragma unroll
        for (int j = 0; j < 4; ++j) {
            int e = (j < cnt) ? e0 + j : e0;
            s[j] = ei[e]; dd[j] = ei[E + e];
        }
    }
#pragma unroll
    for (int j = 0; j < 4; ++j) {
        if (j < cnt) {
            int pos = atomicAdd(&degs[dd[j]], 1);
            if (pos < ELLW) ell[(size_t)dd[j] * ELLW + pos] = (ushort)s[j];
        }
    }
}

// h0 = bf16(x) @ W_lin + b_lin, 128-row tiles; smem = As[4096] | Bs[4096] ushorts (16KB)
__device__ __forceinline__ void lin_gemm_role(int gb, int tid, ushort* smem,
    const float* __restrict__ A, const ushort* __restrict__ Wt,
    const float* __restrict__ bias, ushort* __restrict__ out, int N)
{
    ushort* As = smem;
    ushort* Bs = smem + 4096;
    const int lane = tid & 63;
    const int wave = tid >> 6;
    const int wr = wave >> 1, wc = wave & 1;
    const int row0 = gb * 128;
    const int l15 = lane & 15, quad = lane >> 4;

    frag_cd acc[4][4];
#pragma unroll
    for (int i = 0; i < 4; ++i)
#pragma unroll
        for (int j = 0; j < 4; ++j) acc[i][j] = (frag_cd){0.f, 0.f, 0.f, 0.f};

#pragma unroll 1
    for (int k0 = 0; k0 < 384; k0 += 32) {
        __syncthreads();
#pragma unroll
        for (int i = 0; i < 4; ++i) {
            int e = i * 256 + tid;
            int r = e >> 3, q = e & 7;
            int gr = row0 + r; if (gr > N - 1) gr = N - 1;
            float4 v = *(const float4*)(A + (size_t)gr * 384 + k0 + q * 4);
            ushort4 o; o.x = f2bf(v.x); o.y = f2bf(v.y); o.z = f2bf(v.z); o.w = f2bf(v.w);
            *(ushort4*)(As + r * 32 + q * 4) = o;
        }
#pragma unroll
        for (int i = 0; i < 2; ++i) {
            int e = i * 256 + tid;
            uint4 v = *(const uint4*)(Wt + (size_t)(e >> 2) * 384 + k0 + (e & 3) * 8);
            *(uint4*)(Bs + e * 8) = v;
        }
        __syncthreads();

        frag_ab a[4], b[4];
#pragma unroll
        for (int i = 0; i < 4; ++i)
            a[i] = *(const frag_ab*)(As + (wr * 64 + i * 16 + l15) * 32 + quad * 8);
#pragma unroll
        for (int j = 0; j < 4; ++j)
            b[j] = *(const frag_ab*)(Bs + (wc * 64 + j * 16 + l15) * 32 + quad * 8);
#pragma unroll
        for (int i = 0; i < 4; ++i)
#pragma unroll
            for (int j = 0; j < 4; ++j)
                acc[i][j] = __builtin_amdgcn_mfma_f32_16x16x32_bf16(a[i], b[j], acc[i][j], 0, 0, 0);
    }

#pragma unroll
    for (int i = 0; i < 4; ++i)
#pragma unroll
        for (int r = 0; r < 4; ++r) {
            int row = row0 + wr * 64 + i * 16 + quad * 4 + r;
            if (row < N)
#pragma unroll
                for (int j = 0; j < 4; ++j) {
                    int col = wc * 64 + j * 16 + l15;
                    out[(size_t)row * 128 + col] = f2bf(acc[i][j][r] + bias[col]);
                }
        }
}

__device__ __forceinline__ void acc8(float* acc, uint4 v) {
    acc[0] += bf2f((ushort)(v.x & 0xffff)); acc[1] += bf2f((ushort)(v.x >> 16));
    acc[2] += bf2f((ushort)(v.y & 0xffff)); acc[3] += bf2f((ushort)(v.y >> 16));
    acc[4] += bf2f((ushort)(v.z & 0xffff)); acc[5] += bf2f((ushort)(v.z >> 16));
    acc[6] += bf2f((ushort)(v.w & 0xffff)); acc[7] += bf2f((ushort)(v.w >> 16));
}

// fused ELL mean-aggregate + dual GEMM (round-6 28KB layout, 44us each)
// smem = Ms[8192] | As[2048] | Bs[4096] ushorts (28KB)
__device__ __forceinline__ void agg_role(int ab, int tid, ushort* smem,
    const ushort* __restrict__ h, const ushort* __restrict__ ell,
    const int* __restrict__ degs,
    const ushort* __restrict__ Wtl, const ushort* __restrict__ Wtr,
    const float* __restrict__ bias, ushort* __restrict__ out, int N, bool relu)
{
    ushort* Ms = smem;           // chunk c of row r at c ^ (r&7)
    ushort* As = smem + 8192;    // chunk swizzle kq ^ (r&3)
    ushort* Bs = smem + 10240;   // chunk swizzle bk ^ (br&3)
    const int lane = tid & 63;
    const int wave = tid >> 6;
    const int row0 = ab * 64;
    const int g = lane >> 4;
    const int q = lane & 15;

#pragma unroll 1
    for (int it = 0; it < 4; ++it) {
        int r = (wave << 4) + (it << 2) + g;
        int node = row0 + r;
        int nd = node < N ? node : N - 1;
        const ushort* erow = ell + (size_t)nd * ELLW;
        int d = degs[nd];
        int dc = d < ELLW ? d : ELLW;
        float acc[8];
#pragma unroll
        for (int k = 0; k < 8; ++k) acc[k] = 0.f;
        int n = 0;
        for (; n + 8 <= dc; n += 8) {
            ushort4 iv0 = *(const ushort4*)(erow + n);
            ushort4 iv1 = *(const ushort4*)(erow + n + 4);
            uint4 v0 = *(const uint4*)(h + (size_t)iv0.x * CH + q * 8);
            uint4 v1 = *(const uint4*)(h + (size_t)iv0.y * CH + q * 8);
            uint4 v2 = *(const uint4*)(h + (size_t)iv0.z * CH + q * 8);
            uint4 v3 = *(const uint4*)(h + (size_t)iv0.w * CH + q * 8);
            uint4 v4 = *(const uint4*)(h + (size_t)iv1.x * CH + q * 8);
            uint4 v5 = *(const uint4*)(h + (size_t)iv1.y * CH + q * 8);
            uint4 v6 = *(const uint4*)(h + (size_t)iv1.z * CH + q * 8);
            uint4 v7 = *(const uint4*)(h + (size_t)iv1.w * CH + q * 8);
            acc8(acc, v0); acc8(acc, v1); acc8(acc, v2); acc8(acc, v3);
            acc8(acc, v4); acc8(acc, v5); acc8(acc, v6); acc8(acc, v7);
        }
        for (; n + 4 <= dc; n += 4) {
            ushort4 iv = *(const ushort4*)(erow + n);
            uint4 v0 = *(const uint4*)(h + (size_t)iv.x * CH + q * 8);
            uint4 v1 = *(const uint4*)(h + (size_t)iv.y * CH + q * 8);
            uint4 v2 = *(const uint4*)(h + (size_t)iv.z * CH + q * 8);
            uint4 v3 = *(const uint4*)(h + (size_t)iv.w * CH + q * 8);
            acc8(acc, v0); acc8(acc, v1); acc8(acc, v2); acc8(acc, v3);
        }
        for (; n < dc; ++n) {
            uint4 v0 = *(const uint4*)(h + (size_t)erow[n] * CH + q * 8);
            acc8(acc, v0);
        }
        float inv = 1.f / fmaxf((float)d, 1.f);
        uint4 o;
        o.x = ((uint)f2bf(acc[1] * inv) << 16) | (uint)f2bf(acc[0] * inv);
        o.y = ((uint)f2bf(acc[3] * inv) << 16) | (uint)f2bf(acc[2] * inv);
        o.z = ((uint)f2bf(acc[5] * inv) << 16) | (uint)f2bf(acc[4] * inv);
        o.w = ((uint)f2bf(acc[7] * inv) << 16) | (uint)f2bf(acc[6] * inv);
        int chunk = q ^ (r & 7);
        *(uint4*)(Ms + r * 128 + chunk * 8) = o;
    }

    const int wr = wave >> 1, wc = wave & 1;
    const int l15 = q, quad = g;

    frag_cd acc2[2][4];
#pragma unroll
    for (int i = 0; i < 2; ++i)
#pragma unroll
        for (int j = 0; j < 4; ++j) acc2[i][j] = (frag_cd){0.f, 0.f, 0.f, 0.f};

#pragma unroll 1
    for (int part = 0; part < 2; ++part) {
        const ushort* Wt = part ? Wtr : Wtl;
#pragma unroll 1
        for (int k0 = 0; k0 < 128; k0 += 32) {
            __syncthreads();   // first pass also orders Ms writes before Ms reads
            if (part) {
                int rr = tid >> 2, kq = tid & 3;
                int gr = row0 + rr; if (gr > N - 1) gr = N - 1;
                uint4 v = *(const uint4*)(h + (size_t)gr * CH + k0 + kq * 8);
                *(uint4*)(As + rr * 32 + ((kq ^ (rr & 3)) * 8)) = v;
            }
#pragma unroll
            for (int i2 = 0; i2 < 2; ++i2) {
                int e = i2 * 256 + tid;
                int br = e >> 2, bk = e & 3;
                uint4 v = *(const uint4*)(Wt + (size_t)br * 128 + k0 + bk * 8);
                *(uint4*)(Bs + br * 32 + ((bk ^ (br & 3)) * 8)) = v;
            }
            __syncthreads();

            frag_ab a[2], b[4];
#pragma unroll
            for (int i = 0; i < 2; ++i) {
                int ar = wr * 32 + i * 16 + l15;
                if (part) {
                    a[i] = *(const frag_ab*)(As + ar * 32 + ((quad ^ (ar & 3)) * 8));
                } else {
                    int ch = ((k0 >> 3) + quad) ^ (ar & 7);
                    a[i] = *(const frag_ab*)(Ms + ar * 128 + ch * 8);
                }
            }
#pragma unroll
            for (int j = 0; j < 4; ++j) {
                int br = wc * 64 + j * 16 + l15;
                b[j] = *(const frag_ab*)(Bs + br * 32 + ((quad ^ (br & 3)) * 8));
            }
#pragma unroll
            for (int i = 0; i < 2; ++i)
#pragma unroll
                for (int j = 0; j < 4; ++j)
                    acc2[i][j] = __builtin_amdgcn_mfma_f32_16x16x32_bf16(a[i], b[j], acc2[i][j], 0, 0, 0);
        }
    }

#pragma unroll
    for (int i = 0; i < 2; ++i)
#pragma unroll
        for (int rr = 0; rr < 4; ++rr) {
            int row = row0 + wr * 32 + i * 16 + quad * 4 + rr;
            if (row < N)
#pragma unroll
                for (int j = 0; j < 4; ++j) {
                    int col = wc * 64 + j * 16 + l15;
                    float v = acc2[i][j][rr] + bias[col];
                    if (relu) v = fmaxf(v, 0.f);
                    out[(size_t)row * 128 + col] = f2bf(v);
                }
        }
}

__device__ __forceinline__ float dot8(uint4 va, uint4 vb) {
    float p = 0.f;
    p += bf2f((ushort)(va.x & 0xffff)) * bf2f((ushort)(vb.x & 0xffff));
    p += bf2f((ushort)(va.x >> 16))    * bf2f((ushort)(vb.x >> 16));
    p += bf2f((ushort)(va.y & 0xffff)) * bf2f((ushort)(vb.y & 0xffff));
    p += bf2f((ushort)(va.y >> 16))    * bf2f((ushort)(vb.y >> 16));
    p += bf2f((ushort)(va.z & 0xffff)) * bf2f((ushort)(vb.z & 0xffff));
    p += bf2f((ushort)(va.z >> 16))    * bf2f((ushort)(vb.z >> 16));
    p += bf2f((ushort)(va.w & 0xffff)) * bf2f((ushort)(vb.w & 0xffff));
    p += bf2f((ushort)(va.w >> 16))    * bf2f((ushort)(vb.w >> 16));
    return p;
}

// classifier: 4 edges / 16-lane group (VGPR-lean for the 5-wave/SIMD cap)
__device__ __forceinline__ void classify_role(int cb, int tid,
    const ushort* __restrict__ h2, const int* __restrict__ eli, int EL,
    float* __restrict__ out)
{
    int gt = cb * 256 + tid;
    int g0 = (gt >> 4) * 4;
    int lane = gt & 15;
    if (g0 >= EL) return;
    bool full = (g0 + 3 < EL);
    int ha[4], ta[4];
    if (full) {
        int4 hv = *(const int4*)(eli + g0);
        int4 tv = *(const int4*)(eli + EL + g0);
        ha[0] = hv.x; ha[1] = hv.y; ha[2] = hv.z; ha[3] = hv.w;
        ta[0] = tv.x; ta[1] = tv.y; ta[2] = tv.z; ta[3] = tv.w;
    } else {
#pragma unroll
        for (int j = 0; j < 4; ++j) {
            int gj = (g0 + j < EL) ? g0 + j : EL - 1;
            ha[j] = eli[gj];
            ta[j] = eli[EL + gj];
        }
    }
    uint4 va[4], vb[4];
#pragma unroll
    for (int j = 0; j < 4; ++j) {
        va[j] = *((const uint4*)(h2 + (size_t)ha[j] * CH) + lane);
        vb[j] = *((const uint4*)(h2 + (size_t)ta[j] * CH) + lane);
    }
    float p[4];
#pragma unroll
    for (int j = 0; j < 4; ++j) p[j] = dot8(va[j], vb[j]);
#pragma unroll
    for (int s = 8; s >= 1; s >>= 1) {
#pragma unroll
        for (int j = 0; j < 4; ++j) p[j] += __shfl_down(p[j], s, 16);
    }
    if (lane == 0) {
        if (full) {
            *(float4*)(out + g0) = make_float4(p[0], p[1], p[2], p[3]);
        } else {
#pragma unroll
            for (int j = 0; j < 4; ++j)
                if (g0 + j < EL) out[g0 + j] = p[j];
        }
    }
}

// ================= cooperative mega-kernel: whole pipeline, one dispatch =================
__global__ __launch_bounds__(256, 5) void mega(
    const float* __restrict__ x, const int* __restrict__ ei, const int* __restrict__ eli,
    const float* __restrict__ Wlin, const float* __restrict__ blin,
    const float* __restrict__ W1l, const float* __restrict__ b1, const float* __restrict__ W1r,
    const float* __restrict__ W2l, const float* __restrict__ b2, const float* __restrict__ W2r,
    float* __restrict__ out,
    ushort* __restrict__ n0, ushort* __restrict__ n1, ushort* __restrict__ n2,
    ushort* __restrict__ WtLin, ushort* __restrict__ Wt1l, ushort* __restrict__ Wt1r,
    ushort* __restrict__ Wt2l, ushort* __restrict__ Wt2r,
    int* __restrict__ degs, ushort* __restrict__ ell, int E, int EL)
{
    __shared__ ushort smem[14336];                 // 28KB: max over phases
    cg::grid_group grid = cg::this_grid();
    const int bid = blockIdx.x;
    const int tid = threadIdx.x;
    const int GSZ = gridDim.x;
    const int N  = NODES;
    const int EB = (E + 1023) / 1024;              // 782 fill blocks
    const int GB = (N + 127) / 128;                // 391 lin gemm tiles
    const int AB = (N + 63) / 64;                  // 782 agg tiles
    const int CB = (EL + 63) / 64;                 // classify chunks (64 edges each)

    // P0: weight transposes (degs zeroed by memset before launch)
    for (int vb = bid; vb < 448; vb += GSZ)
        prep_role(vb, tid, Wlin, W1l, W1r, W2l, W2r, WtLin, Wt1l, Wt1r, Wt2l, Wt2r);
    grid.sync();

    // P1: ELL fill (atomic floor ~55us) overlapped with h0 GEMM — single pass when GSZ>=EB+GB
    for (int vb = bid; vb < EB + GB; vb += GSZ) {
        if (vb < EB) fill_role(vb, tid, ei, E, degs, ell);
        else         lin_gemm_role(vb - EB, tid, smem, x, WtLin, blin, n0, N);
    }
    grid.sync();

    // P2: h1 = relu(mean(h0)@W1l + h0@W1r + b1)
    for (int vb = bid; vb < AB; vb += GSZ)
        agg_role(vb, tid, smem, n0, ell, degs, Wt1l, Wt1r, b1, n2, N, true);
    grid.sync();

    // P3: h2 = mean(h1)@W2l + h1@W2r + b2
    for (int vb = bid; vb < AB; vb += GSZ)
        agg_role(vb, tid, smem, n2, ell, degs, Wt2l, Wt2r, b2, n1, N, false);
    grid.sync();

    // P4: classifier, grid-stride
    for (int cb = bid; cb < CB; cb += GSZ)
        classify_role(cb, tid, n1, eli, EL, out);
}

// ================= fallback wrappers (classic 5-dispatch path) =================
__global__ __launch_bounds__(256) void k_prep(
    const float* Wlin, const float* W1l, const float* W1r,
    const float* W2l, const float* W2r,
    ushort* o0, ushort* o1, ushort* o2, ushort* o3, ushort* o4)
{
    if (blockIdx.x < 448)
        prep_role(blockIdx.x, threadIdx.x, Wlin, W1l, W1r, W2l, W2r, o0, o1, o2, o3, o4);
}

__global__ __launch_bounds__(256) void k_linfill(
    const float* A, const ushort* Wt, const float* bias, ushort* out, int N,
    const int* ei, int E, int* degs, ushort* ell)
{
    __shared__ ushort smem[8192];
    int EB = (E + 1023) / 1024;
    int b = blockIdx.x;
    if (b < EB) fill_role(b, threadIdx.x, ei, E, degs, ell);
    else        lin_gemm_role(b - EB, threadIdx.x, smem, A, Wt, bias, out, N);
}

__global__ __launch_bounds__(256) void k_agg(
    const ushort* h, const ushort* ell, const int* degs,
    const ushort* Wtl, const ushort* Wtr, const float* bias, ushort* out, int N, int relu)
{
    __shared__ ushort smem[14336];
    agg_role(blockIdx.x, threadIdx.x, smem, h, ell, degs, Wtl, Wtr, bias, out, N, relu != 0);
}

__global__ __launch_bounds__(256) void k_cls(
    const ushort* h2, const int* eli, int EL, float* out)
{
    classify_role(blockIdx.x, threadIdx.x, h2, eli, EL, out);
}

extern "C" void kernel_launch(void* const* d_in, const int* in_sizes, int n_in,
                              void* d_out, int out_size, void* d_ws, size_t ws_size,
                              hipStream_t stream) {
    const float* x     = (const float*)d_in[0];
    const int*   ei    = (const int*)d_in[1];
    const int*   eli   = (const int*)d_in[2];
    const float* W_lin = (const float*)d_in[3];
    const float* b_lin = (const float*)d_in[4];
    const float* W1l   = (const float*)d_in[5];
    const float* b1    = (const float*)d_in[6];
    const float* W1r   = (const float*)d_in[7];
    const float* W2l   = (const float*)d_in[8];
    const float* b2    = (const float*)d_in[9];
    const float* W2r   = (const float*)d_in[10];
    float* out = (float*)d_out;

    int E  = in_sizes[1] / 2;
    int EL = in_sizes[2] / 2;
    const int N = NODES;

    char* ws = (char*)d_ws;
    size_t off = 0;
    auto alloc = [&](size_t bytes) -> void* {
        void* p = ws + off;
        off += (bytes + 255) & ~(size_t)255;
        return p;
    };
    ushort* n0    = (ushort*)alloc((size_t)N * CH * sizeof(ushort));  // h0
    ushort* n1    = (ushort*)alloc((size_t)N * CH * sizeof(ushort));  // h2
    ushort* n2    = (ushort*)alloc((size_t)N * CH * sizeof(ushort));  // h1
    ushort* WtLin = (ushort*)alloc((size_t)CH * 384 * sizeof(ushort));
    ushort* Wt1l  = (ushort*)alloc((size_t)CH * CH * sizeof(ushort));
    ushort* Wt1r  = (ushort*)alloc((size_t)CH * CH * sizeof(ushort));
    ushort* Wt2l  = (ushort*)alloc((size_t)CH * CH * sizeof(ushort));
    ushort* Wt2r  = (ushort*)alloc((size_t)CH * CH * sizeof(ushort));
    int* degs = (int*)alloc((size_t)N * sizeof(int));                 // packed
    ushort* ell = (ushort*)alloc((size_t)N * ELLW * sizeof(ushort));
    (void)ws_size; (void)n_in; (void)out_size;

    const int EB = (E + 1023) / 1024;           // 782
    const int GB = (N + 127) / 128;             // 391
    const int AB = (N + 63) / 64;               // 782
    const int CB = (EL + 63) / 64;              // 15625

    // zero degree counters (DMA, stream-ordered, graph-capturable)
    hipMemsetAsync(degs, 0, (size_t)N * sizeof(int), stream);

    // cooperative capacity probe (host-side, cached; no stream ops)
    static int s_grid = 0;
    if (s_grid == 0) {
        int occ = 0, ncu = 0, dev = 0;
        if (hipOccupancyMaxActiveBlocksPerMultiprocessor(&occ, (const void*)mega, 256, 0) == hipSuccess &&
            hipGetDevice(&dev) == hipSuccess) {
            hipDeviceProp_t prop;
            if (hipGetDeviceProperties(&prop, dev) == hipSuccess) ncu = prop.multiProcessorCount;
        }
        s_grid = (occ > 0 && ncu > 0) ? occ * ncu : -1;
    }

    bool coop_done = false;
    if (s_grid >= EB + GB) {                    // need single-pass P1 (1173 blocks resident)
        int grid = s_grid;
        void* args[] = { &x, &ei, &eli, &W_lin, &b_lin, &W1l, &b1, &W1r, &W2l, &b2, &W2r,
                         &out, &n0, &n1, &n2, &WtLin, &Wt1l, &Wt1r, &Wt2l, &Wt2r,
                         &degs, &ell, &E, &EL };
        if (hipLaunchCooperativeKernel((const void*)mega, dim3(grid), dim3(256),
                                       args, 0, stream) == hipSuccess)
            coop_done = true;
    }

    if (!coop_done) {
        // classic 5-dispatch path (round-6 structure)
        k_prep<<<dim3(448), dim3(256), 0, stream>>>(
            W_lin, W1l, W1r, W2l, W2r, WtLin, Wt1l, Wt1r, Wt2l, Wt2r);
        k_linfill<<<dim3(EB + GB), dim3(256), 0, stream>>>(
            x, WtLin, b_lin, n0, N, ei, E, degs, ell);
        k_agg<<<dim3(AB), dim3(256), 0, stream>>>(
            n0, ell, degs, Wt1l, Wt1r, b1, n2, N, 1);
        k_agg<<<dim3(AB), dim3(256), 0, stream>>>(
            n2, ell, degs, Wt2l, Wt2r, b2, n1, N, 0);
        k_cls<<<dim3(CB), dim3(256), 0, stream>>>(n1, eli, EL, out);
    }
}

// Round 10
// 310.236 us; speedup vs baseline: 1.0920x; 1.0920x over previous
//
#include <hip/hip_runtime.h>

#define NODES 50000
#define CH 128
#define ELLW 64

using frag_ab = __attribute__((ext_vector_type(8))) short;   // 8 bf16
using frag_cd = __attribute__((ext_vector_type(4))) float;   // 4 fp32

__device__ __forceinline__ float bf2f(ushort u) {
    union { unsigned u; float f; } v; v.u = ((unsigned)u) << 16; return v.f;
}
__device__ __forceinline__ ushort f2bf(float f) {
    union { float f; unsigned u; } v; v.f = f;
    unsigned r = v.u + 0x7fff + ((v.u >> 16) & 1);   // RNE
    return (ushort)(r >> 16);
}

// ---------------- prep: 5 weight transposes + deg zeroing (packed) ----------------
__global__ void prep_weights(const float* __restrict__ Wlin,
                             const float* __restrict__ W1l, const float* __restrict__ W1r,
                             const float* __restrict__ W2l, const float* __restrict__ W2r,
                             ushort* __restrict__ o0, ushort* __restrict__ o1,
                             ushort* __restrict__ o2, ushort* __restrict__ o3,
                             ushort* __restrict__ o4, int* __restrict__ degs) {
    int b = blockIdx.x;
    if (b >= 448) {
        int i = (b - 448) * 256 + threadIdx.y * 128 + threadIdx.x;
        if (i < NODES) degs[i] = 0;
        return;
    }
    const float* W; ushort* O; int K; int kb;
    if (b < 192) { W = Wlin; O = o0; K = 384; kb = b; }
    else {
        int j = (b - 192) >> 6; kb = (b - 192) & 63; K = 128;
        W = (j == 0) ? W1l : (j == 1) ? W1r : (j == 2) ? W2l : W2r;
        O = (j == 0) ? o1  : (j == 1) ? o2  : (j == 2) ? o3  : o4;
    }
    int k = kb * 2 + threadIdx.y;
    int n = threadIdx.x;
    if (k < K) O[(size_t)n * K + k] = f2bf(W[(size_t)k * 128 + n]);
}

// ---------------- merged: gemm_lin 128-row tiles (blocks < GB) + XCD-local ELL fill ------
// Fill diagnosis (r9 counters): 1.8 TB/s of random 64B-line RMW traffic — lines bounce
// between 8 non-coherent L2s, nothing coalesces. Fix: partition dst-space into 8 ranges,
// range = blockIdx%8 (XCD round-robin heuristic; correctness-safe, atomics stay device
// scope). Each block scans a 1/98 edge chunk (sequential, L3-served) and claims slots
// only for its range -> each node's degs line + 128B ELL row is touched by ONE XCD.
__global__ __launch_bounds__(256) void lin_and_ell(
    const float* __restrict__ A, const ushort* __restrict__ Wt,
    const float* __restrict__ bias, ushort* __restrict__ out, int N, int GB,
    const int* __restrict__ ei, int E, int* __restrict__ degs, ushort* __restrict__ ell)
{
    __shared__ ushort As[128 * 32];
    __shared__ ushort Bs[128 * 32];
    if (blockIdx.x >= GB) {
        const int fb = blockIdx.x - GB;
        const int rr = blockIdx.x & 7;             // dst range, aligned to XCD of this block
        const int chunk = fb >> 3;
        const int RNG = (NODES + 7) / 8;           // 6250
        const int lo = rr * RNG;
        int hi = lo + RNG; if (hi > N) hi = N;
        const int ce = (((E + 97) / 98) + 3) & ~3; // chunk size, multiple of 4
        const int start = chunk * ce;
        int end = start + ce; if (end > E) end = E;
        if (start >= E) return;
        const int* srcp = ei;
        const int* dstp = ei + E;
        if ((E & 3) == 0) {
            for (int e = start + threadIdx.x * 4; e < end; e += 1024) {
                int4 dv = *(const int4*)(dstp + e);
                int4 sv = *(const int4*)(srcp + e);
                if (dv.x >= lo && dv.x < hi) { int p = atomicAdd(&degs[dv.x], 1); if (p < ELLW) ell[(size_t)dv.x * ELLW + p] = (ushort)sv.x; }
                if (dv.y >= lo && dv.y < hi) { int p = atomicAdd(&degs[dv.y], 1); if (p < ELLW) ell[(size_t)dv.y * ELLW + p] = (ushort)sv.y; }
                if (dv.z >= lo && dv.z < hi) { int p = atomicAdd(&degs[dv.z], 1); if (p < ELLW) ell[(size_t)dv.z * ELLW + p] = (ushort)sv.z; }
                if (dv.w >= lo && dv.w < hi) { int p = atomicAdd(&degs[dv.w], 1); if (p < ELLW) ell[(size_t)dv.w * ELLW + p] = (ushort)sv.w; }
            }
        } else {
            for (int e = start + threadIdx.x; e < end; e += 256) {
                int d = dstp[e];
                if (d >= lo && d < hi) { int p = atomicAdd(&degs[d], 1); if (p < ELLW) ell[(size_t)d * ELLW + p] = (ushort)srcp[e]; }
            }
        }
        return;
    }
    const int tid = threadIdx.x;
    const int lane = tid & 63;
    const int wave = tid >> 6;
    const int wr = wave >> 1, wc = wave & 1;
    const int row0 = blockIdx.x * 128;
    const int l15 = lane & 15, quad = lane >> 4;

    frag_cd acc[4][4];
#pragma unroll
    for (int i = 0; i < 4; ++i)
#pragma unroll
        for (int j = 0; j < 4; ++j) acc[i][j] = (frag_cd){0.f, 0.f, 0.f, 0.f};

#pragma unroll 1
    for (int k0 = 0; k0 < 384; k0 += 32) {
        __syncthreads();
#pragma unroll
        for (int i = 0; i < 4; ++i) {
            int e = i * 256 + tid;
            int r = e >> 3, q = e & 7;
            int gr = row0 + r; if (gr > N - 1) gr = N - 1;
            float4 v = *(const float4*)(A + (size_t)gr * 384 + k0 + q * 4);
            ushort4 o; o.x = f2bf(v.x); o.y = f2bf(v.y); o.z = f2bf(v.z); o.w = f2bf(v.w);
            *(ushort4*)(As + r * 32 + q * 4) = o;
        }
#pragma unroll
        for (int i = 0; i < 2; ++i) {
            int e = i * 256 + tid;
            uint4 v = *(const uint4*)(Wt + (size_t)(e >> 2) * 384 + k0 + (e & 3) * 8);
            *(uint4*)(Bs + e * 8) = v;
        }
        __syncthreads();

        frag_ab a[4], b[4];
#pragma unroll
        for (int i = 0; i < 4; ++i)
            a[i] = *(const frag_ab*)(As + (wr * 64 + i * 16 + l15) * 32 + quad * 8);
#pragma unroll
        for (int j = 0; j < 4; ++j)
            b[j] = *(const frag_ab*)(Bs + (wc * 64 + j * 16 + l15) * 32 + quad * 8);
#pragma unroll
        for (int i = 0; i < 4; ++i)
#pragma unroll
            for (int j = 0; j < 4; ++j)
                acc[i][j] = __builtin_amdgcn_mfma_f32_16x16x32_bf16(a[i], b[j], acc[i][j], 0, 0, 0);
    }

#pragma unroll
    for (int i = 0; i < 4; ++i)
#pragma unroll
        for (int r = 0; r < 4; ++r) {
            int row = row0 + wr * 64 + i * 16 + quad * 4 + r;
            if (row < N)
#pragma unroll
                for (int j = 0; j < 4; ++j) {
                    int col = wc * 64 + j * 16 + l15;
                    out[(size_t)row * 128 + col] = f2bf(acc[i][j][r] + bias[col]);
                }
        }
}

// ---------------- helpers ----------------
__device__ __forceinline__ void acc8(float* acc, uint4 v) {
    acc[0] += bf2f((ushort)(v.x & 0xffff)); acc[1] += bf2f((ushort)(v.x >> 16));
    acc[2] += bf2f((ushort)(v.y & 0xffff)); acc[3] += bf2f((ushort)(v.y >> 16));
    acc[4] += bf2f((ushort)(v.z & 0xffff)); acc[5] += bf2f((ushort)(v.z >> 16));
    acc[6] += bf2f((ushort)(v.w & 0xffff)); acc[7] += bf2f((ushort)(v.w >> 16));
}

// ---------------- fused: ELL mean-aggregate + dual GEMM (round-6 28KB layout) -----------
template <bool RELU>
__global__ __launch_bounds__(256) void agg_gemm(
    const ushort* __restrict__ h, const ushort* __restrict__ ell,
    const int* __restrict__ degs,
    const ushort* __restrict__ Wtl, const ushort* __restrict__ Wtr,
    const float* __restrict__ bias, ushort* __restrict__ out, int N)
{
    __shared__ ushort Ms[64 * 128];   // chunk c of row r stored at c ^ (r&7)
    __shared__ ushort As[64 * 32];    // chunk swizzle kq ^ (r&3)
    __shared__ ushort Bs[128 * 32];   // chunk swizzle bk ^ (br&3)
    const int tid = threadIdx.x;
    const int lane = tid & 63;
    const int wave = tid >> 6;
    const int row0 = blockIdx.x * 64;
    const int g = lane >> 4;
    const int q = lane & 15;

    // ---- phase 1: mean aggregation into Ms (8-deep neighbor ILP) ----
#pragma unroll 1
    for (int it = 0; it < 4; ++it) {
        int r = (wave << 4) + (it << 2) + g;
        int node = row0 + r;
        int nd = node < N ? node : N - 1;
        const ushort* erow = ell + (size_t)nd * ELLW;
        int d = degs[nd];
        int dc = d < ELLW ? d : ELLW;
        float acc[8];
#pragma unroll
        for (int k = 0; k < 8; ++k) acc[k] = 0.f;
        int n = 0;
        for (; n + 8 <= dc; n += 8) {
            ushort4 iv0 = *(const ushort4*)(erow + n);
            ushort4 iv1 = *(const ushort4*)(erow + n + 4);
            uint4 v0 = *(const uint4*)(h + (size_t)iv0.x * CH + q * 8);
            uint4 v1 = *(const uint4*)(h + (size_t)iv0.y * CH + q * 8);
            uint4 v2 = *(const uint4*)(h + (size_t)iv0.z * CH + q * 8);
            uint4 v3 = *(const uint4*)(h + (size_t)iv0.w * CH + q * 8);
            uint4 v4 = *(const uint4*)(h + (size_t)iv1.x * CH + q * 8);
            uint4 v5 = *(const uint4*)(h + (size_t)iv1.y * CH + q * 8);
            uint4 v6 = *(const uint4*)(h + (size_t)iv1.z * CH + q * 8);
            uint4 v7 = *(const uint4*)(h + (size_t)iv1.w * CH + q * 8);
            acc8(acc, v0); acc8(acc, v1); acc8(acc, v2); acc8(acc, v3);
            acc8(acc, v4); acc8(acc, v5); acc8(acc, v6); acc8(acc, v7);
        }
        for (; n + 4 <= dc; n += 4) {
            ushort4 iv = *(const ushort4*)(erow + n);
            uint4 v0 = *(const uint4*)(h + (size_t)iv.x * CH + q * 8);
            uint4 v1 = *(const uint4*)(h + (size_t)iv.y * CH + q * 8);
            uint4 v2 = *(const uint4*)(h + (size_t)iv.z * CH + q * 8);
            uint4 v3 = *(const uint4*)(h + (size_t)iv.w * CH + q * 8);
            acc8(acc, v0); acc8(acc, v1); acc8(acc, v2); acc8(acc, v3);
        }
        for (; n < dc; ++n) {
            uint4 v0 = *(const uint4*)(h + (size_t)erow[n] * CH + q * 8);
            acc8(acc, v0);
        }
        float inv = 1.f / fmaxf((float)d, 1.f);
        uint4 o;
        o.x = ((uint)f2bf(acc[1] * inv) << 16) | (uint)f2bf(acc[0] * inv);
        o.y = ((uint)f2bf(acc[3] * inv) << 16) | (uint)f2bf(acc[2] * inv);
        o.z = ((uint)f2bf(acc[5] * inv) << 16) | (uint)f2bf(acc[4] * inv);
        o.w = ((uint)f2bf(acc[7] * inv) << 16) | (uint)f2bf(acc[6] * inv);
        int chunk = q ^ (r & 7);
        *(uint4*)(Ms + r * 128 + chunk * 8) = o;
    }

    // ---- phase 2: dual GEMM ----
    const int wr = wave >> 1, wc = wave & 1;
    const int l15 = q, quad = g;

    frag_cd acc2[2][4];
#pragma unroll
    for (int i = 0; i < 2; ++i)
#pragma unroll
        for (int j = 0; j < 4; ++j) acc2[i][j] = (frag_cd){0.f, 0.f, 0.f, 0.f};

#pragma unroll 1
    for (int part = 0; part < 2; ++part) {
        const ushort* Wt = part ? Wtr : Wtl;
#pragma unroll 1
        for (int k0 = 0; k0 < 128; k0 += 32) {
            __syncthreads();   // first pass also orders Ms writes before Ms reads
            if (part) {
                int rr = tid >> 2, kq = tid & 3;
                int gr = row0 + rr; if (gr > N - 1) gr = N - 1;
                uint4 v = *(const uint4*)(h + (size_t)gr * CH + k0 + kq * 8);
                *(uint4*)(As + rr * 32 + ((kq ^ (rr & 3)) * 8)) = v;
            }
#pragma unroll
            for (int i2 = 0; i2 < 2; ++i2) {
                int e = i2 * 256 + tid;
                int br = e >> 2, bk = e & 3;
                uint4 v = *(const uint4*)(Wt + (size_t)br * 128 + k0 + bk * 8);
                *(uint4*)(Bs + br * 32 + ((bk ^ (br & 3)) * 8)) = v;
            }
            __syncthreads();

            frag_ab a[2], b[4];
#pragma unroll
            for (int i = 0; i < 2; ++i) {
                int ar = wr * 32 + i * 16 + l15;
                if (part) {
                    a[i] = *(const frag_ab*)(As + ar * 32 + ((quad ^ (ar & 3)) * 8));
                } else {
                    int ch = ((k0 >> 3) + quad) ^ (ar & 7);
                    a[i] = *(const frag_ab*)(Ms + ar * 128 + ch * 8);
                }
            }
#pragma unroll
            for (int j = 0; j < 4; ++j) {
                int br = wc * 64 + j * 16 + l15;
                b[j] = *(const frag_ab*)(Bs + br * 32 + ((quad ^ (br & 3)) * 8));
            }
#pragma unroll
            for (int i = 0; i < 2; ++i)
#pragma unroll
                for (int j = 0; j < 4; ++j)
                    acc2[i][j] = __builtin_amdgcn_mfma_f32_16x16x32_bf16(a[i], b[j], acc2[i][j], 0, 0, 0);
        }
    }

#pragma unroll
    for (int i = 0; i < 2; ++i)
#pragma unroll
        for (int rr = 0; rr < 4; ++rr) {
            int row = row0 + wr * 32 + i * 16 + quad * 4 + rr;
            if (row < N)
#pragma unroll
                for (int j = 0; j < 4; ++j) {
                    int col = wc * 64 + j * 16 + l15;
                    float v = acc2[i][j][rr] + bias[col];
                    if (RELU) v = fmaxf(v, 0.f);
                    out[(size_t)row * 128 + col] = f2bf(v);
                }
        }
}

// ---------------- classifier: 8 edges / 16-lane group ----------------
__device__ __forceinline__ float dot8(uint4 va, uint4 vb) {
    float p = 0.f;
    p += bf2f((ushort)(va.x & 0xffff)) * bf2f((ushort)(vb.x & 0xffff));
    p += bf2f((ushort)(va.x >> 16))    * bf2f((ushort)(vb.x >> 16));
    p += bf2f((ushort)(va.y & 0xffff)) * bf2f((ushort)(vb.y & 0xffff));
    p += bf2f((ushort)(va.y >> 16))    * bf2f((ushort)(vb.y >> 16));
    p += bf2f((ushort)(va.z & 0xffff)) * bf2f((ushort)(vb.z & 0xffff));
    p += bf2f((ushort)(va.z >> 16))    * bf2f((ushort)(vb.z >> 16));
    p += bf2f((ushort)(va.w & 0xffff)) * bf2f((ushort)(vb.w & 0xffff));
    p += bf2f((ushort)(va.w >> 16))    * bf2f((ushort)(vb.w >> 16));
    return p;
}

__global__ __launch_bounds__(256) void classify_bf(
    const ushort* __restrict__ h2, const int* __restrict__ eli,
    int EL, float* __restrict__ out) {
    int gt = blockIdx.x * blockDim.x + threadIdx.x;
    int g0 = (gt >> 4) * 8;
    int lane = gt & 15;
    if (g0 >= EL) return;
    bool full = (g0 + 7 < EL);
    int ha[8], ta[8];
    if (full) {
        int4 h0 = *(const int4*)(eli + g0);
        int4 h1 = *(const int4*)(eli + g0 + 4);
        int4 t0 = *(const int4*)(eli + EL + g0);
        int4 t1 = *(const int4*)(eli + EL + g0 + 4);
        ha[0] = h0.x; ha[1] = h0.y; ha[2] = h0.z; ha[3] = h0.w;
        ha[4] = h1.x; ha[5] = h1.y; ha[6] = h1.z; ha[7] = h1.w;
        ta[0] = t0.x; ta[1] = t0.y; ta[2] = t0.z; ta[3] = t0.w;
        ta[4] = t1.x; ta[5] = t1.y; ta[6] = t1.z; ta[7] = t1.w;
    } else {
#pragma unroll
        for (int j = 0; j < 8; ++j) {
            int gj = (g0 + j < EL) ? g0 + j : EL - 1;
            ha[j] = eli[gj];
            ta[j] = eli[EL + gj];
        }
    }
    uint4 va[8], vb[8];
#pragma unroll
    for (int j = 0; j < 8; ++j) {
        va[j] = *((const uint4*)(h2 + (size_t)ha[j] * CH) + lane);
        vb[j] = *((const uint4*)(h2 + (size_t)ta[j] * CH) + lane);
    }
    float p[8];
#pragma unroll
    for (int j = 0; j < 8; ++j) p[j] = dot8(va[j], vb[j]);
#pragma unroll
    for (int s = 8; s >= 1; s >>= 1) {
#pragma unroll
        for (int j = 0; j < 8; ++j) p[j] += __shfl_down(p[j], s, 16);
    }
    if (lane == 0) {
        if (full) {
            *(float4*)(out + g0)     = make_float4(p[0], p[1], p[2], p[3]);
            *(float4*)(out + g0 + 4) = make_float4(p[4], p[5], p[6], p[7]);
        } else {
#pragma unroll
            for (int j = 0; j < 8; ++j)
                if (g0 + j < EL) out[g0 + j] = p[j];
        }
    }
}

extern "C" void kernel_launch(void* const* d_in, const int* in_sizes, int n_in,
                              void* d_out, int out_size, void* d_ws, size_t ws_size,
                              hipStream_t stream) {
    const float* x     = (const float*)d_in[0];
    const int*   ei    = (const int*)d_in[1];
    const int*   eli   = (const int*)d_in[2];
    const float* W_lin = (const float*)d_in[3];
    const float* b_lin = (const float*)d_in[4];
    const float* W1l   = (const float*)d_in[5];
    const float* b1    = (const float*)d_in[6];
    const float* W1r   = (const float*)d_in[7];
    const float* W2l   = (const float*)d_in[8];
    const float* b2    = (const float*)d_in[9];
    const float* W2r   = (const float*)d_in[10];
    float* out = (float*)d_out;

    const int E  = in_sizes[1] / 2;
    const int EL = in_sizes[2] / 2;
    const int N  = NODES;

    char* ws = (char*)d_ws;
    size_t off = 0;
    auto alloc = [&](size_t bytes) -> void* {
        void* p = ws + off;
        off += (bytes + 255) & ~(size_t)255;
        return p;
    };
    ushort* n0    = (ushort*)alloc((size_t)N * CH * sizeof(ushort));  // h0
    ushort* n1    = (ushort*)alloc((size_t)N * CH * sizeof(ushort));  // h2
    ushort* n2    = (ushort*)alloc((size_t)N * CH * sizeof(ushort));  // h1
    ushort* WtLin = (ushort*)alloc((size_t)CH * 384 * sizeof(ushort));
    ushort* Wt1l  = (ushort*)alloc((size_t)CH * CH * sizeof(ushort));
    ushort* Wt1r  = (ushort*)alloc((size_t)CH * CH * sizeof(ushort));
    ushort* Wt2l  = (ushort*)alloc((size_t)CH * CH * sizeof(ushort));
    ushort* Wt2r  = (ushort*)alloc((size_t)CH * CH * sizeof(ushort));
    int* degs = (int*)alloc((size_t)N * sizeof(int));                 // packed
    ushort* ell = (ushort*)alloc((size_t)N * ELLW * sizeof(ushort));
    (void)ws_size; (void)n_in; (void)out_size;

    const int GB128 = (N + 127) / 128;                    // 391 gemm tiles
    const int ce     = (((E + 97) / 98) + 3) & ~3;        // edge chunk (mult of 4)
    const int chunks = (E + ce - 1) / ce;                 // 98
    const int FB     = chunks * 8;                        // 784 fill blocks (chunk x range)
    const int AB64   = (N + 63) / 64;                     // 782 fused agg_gemm blocks

    // 1) weight transposes + deg zeroing
    prep_weights<<<dim3(644), dim3(128, 2), 0, stream>>>(
        W_lin, W1l, W1r, W2l, W2r, WtLin, Wt1l, Wt1r, Wt2l, Wt2r, degs);

    // 2) h0 = bf16(x)@W_lin + b_lin  OVERLAPPED WITH  XCD-local ELL build
    lin_and_ell<<<dim3(GB128 + FB), dim3(256), 0, stream>>>(
        x, WtLin, b_lin, n0, N, GB128, ei, E, degs, ell);

    // 3) layer 1 fused: h1 = relu(mean(h0)@W1l + h0@W1r + b1) -> n2
    agg_gemm<true><<<dim3(AB64), dim3(256), 0, stream>>>(
        n0, ell, degs, Wt1l, Wt1r, b1, n2, N);

    // 4) layer 2 fused: h2 = mean(h1)@W2l + h1@W2r + b2 -> n1
    agg_gemm<false><<<dim3(AB64), dim3(256), 0, stream>>>(
        n2, ell, degs, Wt2l, Wt2r, b2, n1, N);

    // 5) classifier on h2 = n1
    long long groups = ((long long)EL + 7) / 8;
    long long cls_threads = groups * 16;
    classify_bf<<<dim3((int)((cls_threads + 255) / 256)), dim3(256), 0, stream>>>(
        n1, eli, EL, out);
}

// Round 11
// 299.017 us; speedup vs baseline: 1.1329x; 1.0375x over previous
//
#include <hip/hip_runtime.h>

#define NODES 50000
#define CH 128
#define ELLW 64

using frag_ab = __attribute__((ext_vector_type(8))) short;   // 8 bf16
using frag_cd = __attribute__((ext_vector_type(4))) float;   // 4 fp32

__device__ __forceinline__ float bf2f(ushort u) {
    union { unsigned u; float f; } v; v.u = ((unsigned)u) << 16; return v.f;
}
__device__ __forceinline__ ushort f2bf(float f) {
    union { float f; unsigned u; } v; v.f = f;
    unsigned r = v.u + 0x7fff + ((v.u >> 16) & 1);   // RNE
    return (ushort)(r >> 16);
}

// ---------------- prep: 5 weight transposes + deg zeroing (stride-16 counters) ------------
__global__ void prep_weights(const float* __restrict__ Wlin,
                             const float* __restrict__ W1l, const float* __restrict__ W1r,
                             const float* __restrict__ W2l, const float* __restrict__ W2r,
                             ushort* __restrict__ o0, ushort* __restrict__ o1,
                             ushort* __restrict__ o2, ushort* __restrict__ o3,
                             ushort* __restrict__ o4, int* __restrict__ degs) {
    int b = blockIdx.x;
    if (b >= 448) {
        int i = (b - 448) * 256 + threadIdx.y * 128 + threadIdx.x;
        if (i < NODES) degs[i << 4] = 0;
        return;
    }
    const float* W; ushort* O; int K; int kb;
    if (b < 192) { W = Wlin; O = o0; K = 384; kb = b; }
    else {
        int j = (b - 192) >> 6; kb = (b - 192) & 63; K = 128;
        W = (j == 0) ? W1l : (j == 1) ? W1r : (j == 2) ? W2l : W2r;
        O = (j == 0) ? o1  : (j == 1) ? o2  : (j == 2) ? o3  : o4;
    }
    int k = kb * 2 + threadIdx.y;
    int n = threadIdx.x;
    if (k < K) O[(size_t)n * K + k] = f2bf(W[(size_t)k * 128 + n]);
}

// ---------------- merged: gemm_lin 128-row tiles (blocks < GB) + fill_ell ----------------
// Fill role is at its global-atomic floor (~55us): contention spreading, ILP, ushort ELL,
// LDS-scan (674us), and XCD-partition (70us) all fail to beat it. GEMM role hides under it.
__global__ __launch_bounds__(256) void lin_and_ell(
    const float* __restrict__ A, const ushort* __restrict__ Wt,
    const float* __restrict__ bias, ushort* __restrict__ out, int N, int GB,
    const int* __restrict__ ei, int E, int* __restrict__ degs, ushort* __restrict__ ell)
{
    __shared__ ushort As[128 * 32];
    __shared__ ushort Bs[128 * 32];
    if (blockIdx.x >= GB) {
        int e0 = ((blockIdx.x - GB) * 256 + threadIdx.x) * 4;
        if (e0 >= E) return;
        int s[4], dd[4], cnt;
        if (((E & 3) == 0) && (e0 + 3 < E)) {
            int4 sv = *(const int4*)(ei + e0);
            int4 dv = *(const int4*)(ei + E + e0);
            s[0] = sv.x; s[1] = sv.y; s[2] = sv.z; s[3] = sv.w;
            dd[0] = dv.x; dd[1] = dv.y; dd[2] = dv.z; dd[3] = dv.w;
            cnt = 4;
        } else {
            cnt = E - e0; if (cnt > 4) cnt = 4;
#pragma unroll
            for (int j = 0; j < 4; ++j) {
                int e = (j < cnt) ? e0 + j : e0;
                s[j] = ei[e]; dd[j] = ei[E + e];
            }
        }
#pragma unroll
        for (int j = 0; j < 4; ++j) {
            if (j < cnt) {
                int pos = atomicAdd(&degs[dd[j] << 4], 1);
                if (pos < ELLW) ell[(size_t)dd[j] * ELLW + pos] = (ushort)s[j];
            }
        }
        return;
    }
    const int tid = threadIdx.x;
    const int lane = tid & 63;
    const int wave = tid >> 6;
    const int wr = wave >> 1, wc = wave & 1;
    const int row0 = blockIdx.x * 128;
    const int l15 = lane & 15, quad = lane >> 4;

    frag_cd acc[4][4];
#pragma unroll
    for (int i = 0; i < 4; ++i)
#pragma unroll
        for (int j = 0; j < 4; ++j) acc[i][j] = (frag_cd){0.f, 0.f, 0.f, 0.f};

#pragma unroll 1
    for (int k0 = 0; k0 < 384; k0 += 32) {
        __syncthreads();
#pragma unroll
        for (int i = 0; i < 4; ++i) {
            int e = i * 256 + tid;
            int r = e >> 3, q = e & 7;
            int gr = row0 + r; if (gr > N - 1) gr = N - 1;
            float4 v = *(const float4*)(A + (size_t)gr * 384 + k0 + q * 4);
            ushort4 o; o.x = f2bf(v.x); o.y = f2bf(v.y); o.z = f2bf(v.z); o.w = f2bf(v.w);
            *(ushort4*)(As + r * 32 + q * 4) = o;
        }
#pragma unroll
        for (int i = 0; i < 2; ++i) {
            int e = i * 256 + tid;
            uint4 v = *(const uint4*)(Wt + (size_t)(e >> 2) * 384 + k0 + (e & 3) * 8);
            *(uint4*)(Bs + e * 8) = v;
        }
        __syncthreads();

        frag_ab a[4], b[4];
#pragma unroll
        for (int i = 0; i < 4; ++i)
            a[i] = *(const frag_ab*)(As + (wr * 64 + i * 16 + l15) * 32 + quad * 8);
#pragma unroll
        for (int j = 0; j < 4; ++j)
            b[j] = *(const frag_ab*)(Bs + (wc * 64 + j * 16 + l15) * 32 + quad * 8);
#pragma unroll
        for (int i = 0; i < 4; ++i)
#pragma unroll
            for (int j = 0; j < 4; ++j)
                acc[i][j] = __builtin_amdgcn_mfma_f32_16x16x32_bf16(a[i], b[j], acc[i][j], 0, 0, 0);
    }

#pragma unroll
    for (int i = 0; i < 4; ++i)
#pragma unroll
        for (int r = 0; r < 4; ++r) {
            int row = row0 + wr * 64 + i * 16 + quad * 4 + r;
            if (row < N)
#pragma unroll
                for (int j = 0; j < 4; ++j) {
                    int col = wc * 64 + j * 16 + l15;
                    out[(size_t)row * 128 + col] = f2bf(acc[i][j][r] + bias[col]);
                }
        }
}

// ---------------- helpers ----------------
__device__ __forceinline__ void acc8(float* acc, uint4 v) {
    acc[0] += bf2f((ushort)(v.x & 0xffff)); acc[1] += bf2f((ushort)(v.x >> 16));
    acc[2] += bf2f((ushort)(v.y & 0xffff)); acc[3] += bf2f((ushort)(v.y >> 16));
    acc[4] += bf2f((ushort)(v.z & 0xffff)); acc[5] += bf2f((ushort)(v.z >> 16));
    acc[6] += bf2f((ushort)(v.w & 0xffff)); acc[7] += bf2f((ushort)(v.w >> 16));
}

// ---------------- fused: ELL mean-aggregate + dual GEMM (28KB LDS, best-known) ----------
template <bool RELU>
__global__ __launch_bounds__(256) void agg_gemm(
    const ushort* __restrict__ h, const ushort* __restrict__ ell,
    const int* __restrict__ degs,
    const ushort* __restrict__ Wtl, const ushort* __restrict__ Wtr,
    const float* __restrict__ bias, ushort* __restrict__ out, int N)
{
    __shared__ ushort Ms[64 * 128];   // chunk c of row r stored at c ^ (r&7)
    __shared__ ushort As[64 * 32];    // chunk swizzle kq ^ (r&3)
    __shared__ ushort Bs[128 * 32];   // chunk swizzle bk ^ (br&3)
    const int tid = threadIdx.x;
    const int lane = tid & 63;
    const int wave = tid >> 6;
    const int row0 = blockIdx.x * 64;
    const int g = lane >> 4;
    const int q = lane & 15;

    // ---- phase 1: mean aggregation into Ms (8-deep neighbor ILP) ----
#pragma unroll 1
    for (int it = 0; it < 4; ++it) {
        int r = (wave << 4) + (it << 2) + g;
        int node = row0 + r;
        int nd = node < N ? node : N - 1;
        const ushort* erow = ell + (size_t)nd * ELLW;
        int d = degs[nd << 4];
        int dc = d < ELLW ? d : ELLW;
        float acc[8];
#pragma unroll
        for (int k = 0; k < 8; ++k) acc[k] = 0.f;
        int n = 0;
        for (; n + 8 <= dc; n += 8) {
            ushort4 iv0 = *(const ushort4*)(erow + n);
            ushort4 iv1 = *(const ushort4*)(erow + n + 4);
            uint4 v0 = *(const uint4*)(h + (size_t)iv0.x * CH + q * 8);
            uint4 v1 = *(const uint4*)(h + (size_t)iv0.y * CH + q * 8);
            uint4 v2 = *(const uint4*)(h + (size_t)iv0.z * CH + q * 8);
            uint4 v3 = *(const uint4*)(h + (size_t)iv0.w * CH + q * 8);
            uint4 v4 = *(const uint4*)(h + (size_t)iv1.x * CH + q * 8);
            uint4 v5 = *(const uint4*)(h + (size_t)iv1.y * CH + q * 8);
            uint4 v6 = *(const uint4*)(h + (size_t)iv1.z * CH + q * 8);
            uint4 v7 = *(const uint4*)(h + (size_t)iv1.w * CH + q * 8);
            acc8(acc, v0); acc8(acc, v1); acc8(acc, v2); acc8(acc, v3);
            acc8(acc, v4); acc8(acc, v5); acc8(acc, v6); acc8(acc, v7);
        }
        for (; n + 4 <= dc; n += 4) {
            ushort4 iv = *(const ushort4*)(erow + n);
            uint4 v0 = *(const uint4*)(h + (size_t)iv.x * CH + q * 8);
            uint4 v1 = *(const uint4*)(h + (size_t)iv.y * CH + q * 8);
            uint4 v2 = *(const uint4*)(h + (size_t)iv.z * CH + q * 8);
            uint4 v3 = *(const uint4*)(h + (size_t)iv.w * CH + q * 8);
            acc8(acc, v0); acc8(acc, v1); acc8(acc, v2); acc8(acc, v3);
        }
        for (; n < dc; ++n) {
            uint4 v0 = *(const uint4*)(h + (size_t)erow[n] * CH + q * 8);
            acc8(acc, v0);
        }
        float inv = 1.f / fmaxf((float)d, 1.f);
        uint4 o;
        o.x = ((uint)f2bf(acc[1] * inv) << 16) | (uint)f2bf(acc[0] * inv);
        o.y = ((uint)f2bf(acc[3] * inv) << 16) | (uint)f2bf(acc[2] * inv);
        o.z = ((uint)f2bf(acc[5] * inv) << 16) | (uint)f2bf(acc[4] * inv);
        o.w = ((uint)f2bf(acc[7] * inv) << 16) | (uint)f2bf(acc[6] * inv);
        int chunk = q ^ (r & 7);
        *(uint4*)(Ms + r * 128 + chunk * 8) = o;
    }

    // ---- phase 2: dual GEMM ----
    const int wr = wave >> 1, wc = wave & 1;
    const int l15 = q, quad = g;

    frag_cd acc2[2][4];
#pragma unroll
    for (int i = 0; i < 2; ++i)
#pragma unroll
        for (int j = 0; j < 4; ++j) acc2[i][j] = (frag_cd){0.f, 0.f, 0.f, 0.f};

#pragma unroll 1
    for (int part = 0; part < 2; ++part) {
        const ushort* Wt = part ? Wtr : Wtl;
#pragma unroll 1
        for (int k0 = 0; k0 < 128; k0 += 32) {
            __syncthreads();   // first pass also orders Ms writes before Ms reads
            if (part) {
                int rr = tid >> 2, kq = tid & 3;
                int gr = row0 + rr; if (gr > N - 1) gr = N - 1;
                uint4 v = *(const uint4*)(h + (size_t)gr * CH + k0 + kq * 8);
                *(uint4*)(As + rr * 32 + ((kq ^ (rr & 3)) * 8)) = v;
            }
#pragma unroll
            for (int i2 = 0; i2 < 2; ++i2) {
                int e = i2 * 256 + tid;
                int br = e >> 2, bk = e & 3;
                uint4 v = *(const uint4*)(Wt + (size_t)br * 128 + k0 + bk * 8);
                *(uint4*)(Bs + br * 32 + ((bk ^ (br & 3)) * 8)) = v;
            }
            __syncthreads();

            frag_ab a[2], b[4];
#pragma unroll
            for (int i = 0; i < 2; ++i) {
                int ar = wr * 32 + i * 16 + l15;
                if (part) {
                    a[i] = *(const frag_ab*)(As + ar * 32 + ((quad ^ (ar & 3)) * 8));
                } else {
                    int ch = ((k0 >> 3) + quad) ^ (ar & 7);
                    a[i] = *(const frag_ab*)(Ms + ar * 128 + ch * 8);
                }
            }
#pragma unroll
            for (int j = 0; j < 4; ++j) {
                int br = wc * 64 + j * 16 + l15;
                b[j] = *(const frag_ab*)(Bs + br * 32 + ((quad ^ (br & 3)) * 8));
            }
#pragma unroll
            for (int i = 0; i < 2; ++i)
#pragma unroll
                for (int j = 0; j < 4; ++j)
                    acc2[i][j] = __builtin_amdgcn_mfma_f32_16x16x32_bf16(a[i], b[j], acc2[i][j], 0, 0, 0);
        }
    }

#pragma unroll
    for (int i = 0; i < 2; ++i)
#pragma unroll
        for (int rr = 0; rr < 4; ++rr) {
            int row = row0 + wr * 32 + i * 16 + quad * 4 + rr;
            if (row < N)
#pragma unroll
                for (int j = 0; j < 4; ++j) {
                    int col = wc * 64 + j * 16 + l15;
                    float v = acc2[i][j][rr] + bias[col];
                    if (RELU) v = fmaxf(v, 0.f);
                    out[(size_t)row * 128 + col] = f2bf(v);
                }
        }
}

// ---------------- classifier: 8 edges / 16-lane group ----------------
__device__ __forceinline__ float dot8(uint4 va, uint4 vb) {
    float p = 0.f;
    p += bf2f((ushort)(va.x & 0xffff)) * bf2f((ushort)(vb.x & 0xffff));
    p += bf2f((ushort)(va.x >> 16))    * bf2f((ushort)(vb.x >> 16));
    p += bf2f((ushort)(va.y & 0xffff)) * bf2f((ushort)(vb.y & 0xffff));
    p += bf2f((ushort)(va.y >> 16))    * bf2f((ushort)(vb.y >> 16));
    p += bf2f((ushort)(va.z & 0xffff)) * bf2f((ushort)(vb.z & 0xffff));
    p += bf2f((ushort)(va.z >> 16))    * bf2f((ushort)(vb.z >> 16));
    p += bf2f((ushort)(va.w & 0xffff)) * bf2f((ushort)(vb.w & 0xffff));
    p += bf2f((ushort)(va.w >> 16))    * bf2f((ushort)(vb.w >> 16));
    return p;
}

__global__ __launch_bounds__(256) void classify_bf(
    const ushort* __restrict__ h2, const int* __restrict__ eli,
    int EL, float* __restrict__ out) {
    int gt = blockIdx.x * blockDim.x + threadIdx.x;
    int g0 = (gt >> 4) * 8;
    int lane = gt & 15;
    if (g0 >= EL) return;
    bool full = (g0 + 7 < EL);
    int ha[8], ta[8];
    if (full) {
        int4 h0 = *(const int4*)(eli + g0);
        int4 h1 = *(const int4*)(eli + g0 + 4);
        int4 t0 = *(const int4*)(eli + EL + g0);
        int4 t1 = *(const int4*)(eli + EL + g0 + 4);
        ha[0] = h0.x; ha[1] = h0.y; ha[2] = h0.z; ha[3] = h0.w;
        ha[4] = h1.x; ha[5] = h1.y; ha[6] = h1.z; ha[7] = h1.w;
        ta[0] = t0.x; ta[1] = t0.y; ta[2] = t0.z; ta[3] = t0.w;
        ta[4] = t1.x; ta[5] = t1.y; ta[6] = t1.z; ta[7] = t1.w;
    } else {
#pragma unroll
        for (int j = 0; j < 8; ++j) {
            int gj = (g0 + j < EL) ? g0 + j : EL - 1;
            ha[j] = eli[gj];
            ta[j] = eli[EL + gj];
        }
    }
    uint4 va[8], vb[8];
#pragma unroll
    for (int j = 0; j < 8; ++j) {
        va[j] = *((const uint4*)(h2 + (size_t)ha[j] * CH) + lane);
        vb[j] = *((const uint4*)(h2 + (size_t)ta[j] * CH) + lane);
    }
    float p[8];
#pragma unroll
    for (int j = 0; j < 8; ++j) p[j] = dot8(va[j], vb[j]);
#pragma unroll
    for (int s = 8; s >= 1; s >>= 1) {
#pragma unroll
        for (int j = 0; j < 8; ++j) p[j] += __shfl_down(p[j], s, 16);
    }
    if (lane == 0) {
        if (full) {
            *(float4*)(out + g0)     = make_float4(p[0], p[1], p[2], p[3]);
            *(float4*)(out + g0 + 4) = make_float4(p[4], p[5], p[6], p[7]);
        } else {
#pragma unroll
            for (int j = 0; j < 8; ++j)
                if (g0 + j < EL) out[g0 + j] = p[j];
        }
    }
}

extern "C" void kernel_launch(void* const* d_in, const int* in_sizes, int n_in,
                              void* d_out, int out_size, void* d_ws, size_t ws_size,
                              hipStream_t stream) {
    const float* x     = (const float*)d_in[0];
    const int*   ei    = (const int*)d_in[1];
    const int*   eli   = (const int*)d_in[2];
    const float* W_lin = (const float*)d_in[3];
    const float* b_lin = (const float*)d_in[4];
    const float* W1l   = (const float*)d_in[5];
    const float* b1    = (const float*)d_in[6];
    const float* W1r   = (const float*)d_in[7];
    const float* W2l   = (const float*)d_in[8];
    const float* b2    = (const float*)d_in[9];
    const float* W2r   = (const float*)d_in[10];
    float* out = (float*)d_out;

    const int E  = in_sizes[1] / 2;
    const int EL = in_sizes[2] / 2;
    const int N  = NODES;

    char* ws = (char*)d_ws;
    size_t off = 0;
    auto alloc = [&](size_t bytes) -> void* {
        void* p = ws + off;
        off += (bytes + 255) & ~(size_t)255;
        return p;
    };
    ushort* n0    = (ushort*)alloc((size_t)N * CH * sizeof(ushort));  // h0
    ushort* n1    = (ushort*)alloc((size_t)N * CH * sizeof(ushort));  // h2
    ushort* n2    = (ushort*)alloc((size_t)N * CH * sizeof(ushort));  // h1
    ushort* WtLin = (ushort*)alloc((size_t)CH * 384 * sizeof(ushort));
    ushort* Wt1l  = (ushort*)alloc((size_t)CH * CH * sizeof(ushort));
    ushort* Wt1r  = (ushort*)alloc((size_t)CH * CH * sizeof(ushort));
    ushort* Wt2l  = (ushort*)alloc((size_t)CH * CH * sizeof(ushort));
    ushort* Wt2r  = (ushort*)alloc((size_t)CH * CH * sizeof(ushort));
    int* degs = (int*)alloc((size_t)N * 16 * sizeof(int));  // stride-16: 1 counter / 64B line
    ushort* ell = (ushort*)alloc((size_t)N * ELLW * sizeof(ushort));
    (void)ws_size; (void)n_in; (void)out_size;

    const int GB128 = (N + 127) / 128;          // 391 gemm tiles
    const int EB4   = (E + 1023) / 1024;        // 782 fill blocks (256 thr x 4 edges)
    const int AB64  = (N + 63) / 64;            // 782 fused agg_gemm blocks

    // 1) weight transposes + deg zeroing
    prep_weights<<<dim3(644), dim3(128, 2), 0, stream>>>(
        W_lin, W1l, W1r, W2l, W2r, WtLin, Wt1l, Wt1r, Wt2l, Wt2r, degs);

    // 2) h0 = bf16(x)@W_lin + b_lin  OVERLAPPED WITH  ELL build
    lin_and_ell<<<dim3(GB128 + EB4), dim3(256), 0, stream>>>(
        x, WtLin, b_lin, n0, N, GB128, ei, E, degs, ell);

    // 3) layer 1 fused: h1 = relu(mean(h0)@W1l + h0@W1r + b1) -> n2
    agg_gemm<true><<<dim3(AB64), dim3(256), 0, stream>>>(
        n0, ell, degs, Wt1l, Wt1r, b1, n2, N);

    // 4) layer 2 fused: h2 = mean(h1)@W2l + h1@W2r + b2 -> n1
    agg_gemm<false><<<dim3(AB64), dim3(256), 0, stream>>>(
        n2, ell, degs, Wt2l, Wt2r, b2, n1, N);

    // 5) classifier on h2 = n1
    long long groups = ((long long)EL + 7) / 8;
    long long cls_threads = groups * 16;
    classify_bf<<<dim3((int)((cls_threads + 255) / 256)), dim3(256), 0, stream>>>(
        n1, eli, EL, out);
}